// Round 3
// baseline (3292.729 us; speedup 1.0000x reference)
//
#include <hip/hip_runtime.h>

// RNN: h[t] = tanh(W_h h[t-1] + W_x x[t] + b), out = stacked h (fp32).
//  prep_pack : W_h -> f16 packed Wpk2[(p*8+j)*64+q] = rows r=8q+j, k-group p.
//  xin_gemm  : f16 MFMA GEMM writes u = x@W_x^T + b INTO d_out (M=65536,K=128,N=512).
//  rnn_scan  : 64 wgs (1/batch), 512 thr. Thread (s=tid>>6, q=tid&63) computes
//              8 rows x 8 k-groups; h broadcast reads drop to 8/thread/step.
//              32 W entries PINNED in VGPRs (asm barrier), 32 streamed from L2
//              double-buffered. k-split reduced via LDS partials; 2 barriers/step.

typedef _Float16 h2      __attribute__((ext_vector_type(2)));
typedef _Float16 half4_t __attribute__((ext_vector_type(4)));
typedef _Float16 half8_t __attribute__((ext_vector_type(8)));
typedef float    f32x4   __attribute__((ext_vector_type(4)));

#define T_STEPS 1024
#define B_SZ    64
#define NIN     128
#define NH      512
#define WCOLS   641        // NH + NIN + 1

__device__ __forceinline__ float fdot2_(h2 a, h2 b, float c) {
#if __has_builtin(__builtin_amdgcn_fdot2)
    return __builtin_amdgcn_fdot2(a, b, c, false);
#else
    return c + (float)a.x * (float)b.x + (float)a.y * (float)b.y;
#endif
}

__device__ __forceinline__ float dot8(uint4 wu, uint4 hu, float acc) {
    union { uint4 u; h2 h[4]; } w, hv;
    w.u = wu; hv.u = hu;
    acc = fdot2_(w.h[0], hv.h[0], acc);
    acc = fdot2_(w.h[1], hv.h[1], acc);
    acc = fdot2_(w.h[2], hv.h[2], acc);
    acc = fdot2_(w.h[3], hv.h[3], acc);
    return acc;
}

__device__ __forceinline__ float fast_tanh(float x) {
    float z = x * 2.8853900817779268f;        // 2/ln2
#if __has_builtin(__builtin_amdgcn_exp2f)
    float e = __builtin_amdgcn_exp2f(z);
#else
    float e = exp2f(z);
#endif
#if __has_builtin(__builtin_amdgcn_rcpf)
    return 1.f - 2.f * __builtin_amdgcn_rcpf(e + 1.f);
#else
    return 1.f - 2.f / (e + 1.f);
#endif
}

// ---------------- prep: pack W_h f16 ----------------
// out index o = (p*8 + j)*64 + q  <->  row r = 8q+j, k-group p (8 f16 per entry)
__global__ void prep_pack(const float* __restrict__ w_rec,
                          uint4* __restrict__ Wpk2) {
    int o = blockIdx.x * 256 + threadIdx.x;   // 0..32767
    int q = o & 63, j = (o >> 6) & 7, p = o >> 9;
    int r = 8 * q + j;
    union { uint4 u; _Float16 f[8]; } pk;
#pragma unroll
    for (int e = 0; e < 8; ++e)
        pk.f[e] = (_Float16)w_rec[r * WCOLS + 8 * p + e];
    Wpk2[o] = pk.u;
}

// ---------------- xin GEMM (f16 MFMA): u = x @ W_x^T + b -> d_out ----------------
// tile M=64 x N=128, K=128. 256 thr = 4 waves; wave w -> cols w*32..w*32+31.
__global__ __launch_bounds__(256) void xin_gemm(const float* __restrict__ x,
                                                const float* __restrict__ w_rec,
                                                float* __restrict__ out) {
    __shared__ _Float16 xs[64][136];    // +8 pad: frag reads 2-way max
    __shared__ _Float16 ws[128][136];
    const int tid = threadIdx.x;
    const int m0 = blockIdx.x * 64;
    const int n0 = blockIdx.y * 128;

    // stage x (fp32 -> f16): 64 rows x 128 k
#pragma unroll
    for (int c = 0; c < 8; ++c) {
        int f = tid + 256 * c;                 // 0..2047
        int row = f >> 5, c4 = (f & 31) * 4;
        float4 v = *(const float4*)(x + (long)(m0 + row) * NIN + c4);
        half4_t hv = {(_Float16)v.x, (_Float16)v.y, (_Float16)v.z, (_Float16)v.w};
        *(half4_t*)&xs[row][c4] = hv;
    }
    // stage w_x (rows h'=n0..n0+127, cols 512..639 of w_rec; row stride 641 -> scalar loads)
#pragma unroll
    for (int c = 0; c < 16; ++c) {
        int f = tid + 256 * c;                 // 0..4095
        int row = f >> 5, c4 = (f & 31) * 4;
        const float* src = w_rec + (long)(n0 + row) * WCOLS + NH + c4;
        half4_t hv = {(_Float16)src[0], (_Float16)src[1], (_Float16)src[2], (_Float16)src[3]};
        *(half4_t*)&ws[row][c4] = hv;
    }
    __syncthreads();

    const int lane = tid & 63, w = tid >> 6;
    const int lr = lane & 15, lc = lane >> 4;  // A-row / k-chunk quad
    f32x4 acc[4][2];
#pragma unroll
    for (int mi = 0; mi < 4; ++mi)
#pragma unroll
        for (int ni = 0; ni < 2; ++ni) acc[mi][ni] = (f32x4){0.f, 0.f, 0.f, 0.f};

#pragma unroll
    for (int ki = 0; ki < 4; ++ki) {
        int k0 = ki * 32 + lc * 8;
        half8_t a[4], bf[2];
#pragma unroll
        for (int mi = 0; mi < 4; ++mi) a[mi] = *(half8_t*)&xs[mi * 16 + lr][k0];
#pragma unroll
        for (int ni = 0; ni < 2; ++ni) bf[ni] = *(half8_t*)&ws[w * 32 + ni * 16 + lr][k0];
#pragma unroll
        for (int mi = 0; mi < 4; ++mi)
#pragma unroll
            for (int ni = 0; ni < 2; ++ni)
                acc[mi][ni] = __builtin_amdgcn_mfma_f32_16x16x32_f16(
                    a[mi], bf[ni], acc[mi][ni], 0, 0, 0);
    }
    // epilogue: C/D layout col=lane&15, row=(lane>>4)*4+reg (m89/m91-verified)
#pragma unroll
    for (int ni = 0; ni < 2; ++ni) {
        int col = n0 + w * 32 + ni * 16 + lr;
        float bv = w_rec[(long)col * WCOLS + NH + NIN];
#pragma unroll
        for (int mi = 0; mi < 4; ++mi)
#pragma unroll
            for (int r = 0; r < 4; ++r) {
                long row = m0 + mi * 16 + lc * 4 + r;
                out[row * NH + col] = acc[mi][ni][r] + bv;
            }
    }
}

// ---------------- serial scan ----------------
// thread (s = tid>>6, q = tid&63): rows 8q..8q+7, k-groups 8s..8s+7.
// W entries: rows j=0..3 pinned in 128 VGPRs; rows j=4..7 streamed from L2.
__global__ __launch_bounds__(512, 2) void rnn_scan(float* __restrict__ out,
                                                   const float* __restrict__ h0,
                                                   const uint4* __restrict__ Wpk2) {
    __shared__ uint4 hh[2][NH / 8];     // f16 h state, double buffered (2 KiB)
    __shared__ float part[8][NH + 8];   // k-slice partials, padded (16.25 KiB)

    const int tid = threadIdx.x;
    const int b   = blockIdx.x;
    const int s   = tid >> 6;           // k-slice 0..7
    const int q   = tid & 63;           // row block (rows 8q..8q+7)

    // pinned W: rows j=0..3, groups i=0..7 (global k-group 8s+i)
    uint4 Wp[4][8];
#pragma unroll
    for (int j = 0; j < 4; ++j)
#pragma unroll
        for (int i = 0; i < 8; ++i) {
            Wp[j][i] = Wpk2[((8 * s + i) * 8 + j) * 64 + q];
            asm volatile("" : "+v"(Wp[j][i].x), "+v"(Wp[j][i].y),
                              "+v"(Wp[j][i].z), "+v"(Wp[j][i].w));
        }

    ((_Float16*)hh[0])[tid] = (_Float16)h0[b * NH + tid];
    __syncthreads();

    float* pu = out + (long)b * NH + tid;   // finalize row = tid
    float u_cur = *pu;

    for (int t = 0; t < T_STEPS; ++t) {
        const uint4* hcur = hh[t & 1];
        uint4 h[8];
#pragma unroll
        for (int i = 0; i < 8; ++i) h[i] = hcur[8 * s + i];

        float acc0 = 0.f, acc1 = 0.f, acc2 = 0.f, acc3 = 0.f;
        float acc4 = 0.f, acc5 = 0.f, acc6 = 0.f, acc7 = 0.f;
        uint4 R0[8], R1[8];
        // issue stream row j=4
#pragma unroll
        for (int i = 0; i < 8; ++i) R0[i] = Wpk2[((8 * s + i) * 8 + 4) * 64 + q];
        // prefetch next step's u
        long stride = (t + 1 < T_STEPS) ? (long)B_SZ * NH : 0;
        float u_nxt = pu[stride];
        // pinned rows 0..1
#pragma unroll
        for (int i = 0; i < 8; ++i) acc0 = dot8(Wp[0][i], h[i], acc0);
#pragma unroll
        for (int i = 0; i < 8; ++i) acc1 = dot8(Wp[1][i], h[i], acc1);
        // issue stream row j=5
#pragma unroll
        for (int i = 0; i < 8; ++i) R1[i] = Wpk2[((8 * s + i) * 8 + 5) * 64 + q];
        // pinned rows 2..3
#pragma unroll
        for (int i = 0; i < 8; ++i) acc2 = dot8(Wp[2][i], h[i], acc2);
#pragma unroll
        for (int i = 0; i < 8; ++i) acc3 = dot8(Wp[3][i], h[i], acc3);
        // consume j=4, issue j=6
#pragma unroll
        for (int i = 0; i < 8; ++i) acc4 = dot8(R0[i], h[i], acc4);
#pragma unroll
        for (int i = 0; i < 8; ++i) R0[i] = Wpk2[((8 * s + i) * 8 + 6) * 64 + q];
        // consume j=5, issue j=7
#pragma unroll
        for (int i = 0; i < 8; ++i) acc5 = dot8(R1[i], h[i], acc5);
#pragma unroll
        for (int i = 0; i < 8; ++i) R1[i] = Wpk2[((8 * s + i) * 8 + 7) * 64 + q];
        // consume j=6, j=7
#pragma unroll
        for (int i = 0; i < 8; ++i) acc6 = dot8(R0[i], h[i], acc6);
#pragma unroll
        for (int i = 0; i < 8; ++i) acc7 = dot8(R1[i], h[i], acc7);

        // write k-slice partials: part[s][8q + j]
        float4 p0 = {acc0, acc1, acc2, acc3};
        float4 p1 = {acc4, acc5, acc6, acc7};
        *(float4*)&part[s][8 * q]     = p0;
        *(float4*)&part[s][8 * q + 4] = p1;
        __syncthreads();

        // finalize row r = tid: sum 8 slice partials + u, tanh
        float v = u_cur;
#pragma unroll
        for (int k = 0; k < 8; ++k) v += part[k][tid];
        float hnew = fast_tanh(v);
        *pu = hnew;                                       // fp32 out (in place)
        ((_Float16*)hh[(t + 1) & 1])[tid] = (_Float16)hnew;
        u_cur = u_nxt;
        pu += B_SZ * NH;
        __syncthreads();   // hh next visible; part[] reusable
    }
}

extern "C" void kernel_launch(void* const* d_in, const int* in_sizes, int n_in,
                              void* d_out, int out_size, void* d_ws, size_t ws_size,
                              hipStream_t stream) {
    const float* x     = (const float*)d_in[0];   // (1024,64,128)
    const float* h0    = (const float*)d_in[1];   // (64,512)
    const float* w_rec = (const float*)d_in[2];   // (512,641)
    float* out = (float*)d_out;                   // (1024,64,512)

    uint4* Wpk2 = (uint4*)d_ws;                   // 512 KiB packed W_h (f16)

    prep_pack<<<128, 256, 0, stream>>>(w_rec, Wpk2);

    dim3 gA(T_STEPS * B_SZ / 64, NH / 128);       // 1024 x 4
    xin_gemm<<<gA, 256, 0, stream>>>(x, w_rec, out);

    rnn_scan<<<B_SZ, NH, 0, stream>>>(out, h0, Wpk2);
}